// Round 3
// baseline (506.697 us; speedup 1.0000x reference)
//
#include <hip/hip_runtime.h>
#include <math.h>
#include <stdint.h>
#include <stddef.h>

// ---------- types ----------
typedef short bf16x8 __attribute__((ext_vector_type(8)));   // 8 bf16 (4 VGPRs)
typedef short bf16x4 __attribute__((ext_vector_type(4)));   // 4 bf16 (2 VGPRs)
typedef float f32x4  __attribute__((ext_vector_type(4)));

// problem constants
#define BATCH   8
#define D_IN    1024
#define POSD    32
#define KD      1056          // D_IN + POSD (true inner dim)
#define KP      1088          // K padded to multiple of 64 (pad cols are zero)
#define MBARS   2048
#define MROWS   16384         // BATCH * MBARS
#define NOUT    1024

// fp32 -> bf16 round-to-nearest-even
__device__ __forceinline__ short f2bf(float f) {
    unsigned u = __builtin_bit_cast(unsigned, f);
    u += 0x7fffu + ((u >> 16) & 1u);
    return (short)(u >> 16);
}

// ---------- kernel 1: fused prep ----------
// blocks [0, MROWS): segment-mean (K=4) + fourier features -> h row (stride KP, zero-padded)
// blocks [MROWS, MROWS+1024): W fp32 -> bf16 row cast (stride KP, zero-padded)
__global__ __launch_bounds__(256) void prep(const float* __restrict__ x,
                                            const float* __restrict__ W,
                                            short* __restrict__ h,
                                            short* __restrict__ Wb) {
    const int t = threadIdx.x;
    const int bid = blockIdx.x;
    if (bid < MROWS) {
        // 4 input rows are 16 KB contiguous at x + bid*4096
        const float4* src = (const float4*)(x + (size_t)bid * 4096);
        float4 s0 = src[t], s1 = src[t + 256], s2 = src[t + 512], s3 = src[t + 768];
        bf16x4 o = { f2bf((s0.x + s1.x + s2.x + s3.x) * 0.25f),
                     f2bf((s0.y + s1.y + s2.y + s3.y) * 0.25f),
                     f2bf((s0.z + s1.z + s2.z + s3.z) * 0.25f),
                     f2bf((s0.w + s1.w + s2.w + s3.w) * 0.25f) };
        short* hr = h + (size_t)bid * KP;
        *(bf16x4*)(hr + t * 4) = o;
        if (t < POSD) {
            const int mb = bid & (MBARS - 1);
            float pos = (float)mb * (1.0f / (float)(MBARS - 1));
            float fr  = expf((float)(t & 15) * (6.907755278982137f / 15.0f));
            float ang = pos * fr;
            hr[D_IN + t] = f2bf((t < 16) ? sinf(ang) : cosf(ang));
            hr[KD + t]   = 0;            // K padding
        }
    } else {
        const int r = bid - MROWS;       // 0..1023, one W row per block
        const float* wr = W + (size_t)r * KD;
        short* br = Wb + (size_t)r * KP;
        float4 v = *(const float4*)(wr + t * 4);          // cols 0..1023
        bf16x4 o = { f2bf(v.x), f2bf(v.y), f2bf(v.z), f2bf(v.w) };
        *(bf16x4*)(br + t * 4) = o;
        if (t < 8) {
            float4 u = *(const float4*)(wr + 1024 + t * 4);  // cols 1024..1055
            bf16x4 p = { f2bf(u.x), f2bf(u.y), f2bf(u.z), f2bf(u.w) };
            *(bf16x4*)(br + 1024 + t * 4) = p;
            *(bf16x4*)(br + KD + t * 4)   = (bf16x4){0, 0, 0, 0};  // K padding
        }
    }
}

// ---------- kernel 2: register-resident GEMM, NO LDS, NO barriers ----------
// C[16384,1024] = h[16384,KP] @ Wb^T + bias.
// Block = 4 waves in 2x2 -> 128x128 tile; each wave 64x64 via 4x4 of 16x16x32 MFMA.
// Fragments loaded straight from global (A: HBM/L2 streamed; B: 2.2 MB, L1/L2-hot).
// Frag addressing: lane = (q=lane>>4, r=lane&15) -> row r of the 16-row frag, k-octet q
// (identical math to the LDS reads of the R2 kernel, which passed).
__global__ __launch_bounds__(256) void gemm_reg(const short* __restrict__ A,   // h  [MROWS, KP]
                                                const short* __restrict__ B,   // Wb [NOUT, KP]
                                                const float* __restrict__ bias,
                                                float* __restrict__ C) {
    const int tid  = threadIdx.x;
    const int wave = tid >> 6;
    const int lane = tid & 63;
    const int wrow = wave >> 1;
    const int wcol = wave & 1;

    // XCD-aware swizzle: bid%8 = XCD (heuristic). Each XCD owns 16 consecutive
    // m-tiles and walks all 8 n-tiles per m-tile -> the 8 blocks sharing an
    // A-slab co-reside on one XCD -> A fetched from HBM ~once.
    const int bid = blockIdx.x;                 // 0..1023
    const int l   = bid >> 3;                   // 0..127
    const int mt  = (bid & 7) * 16 + (l >> 3);  // 0..127
    const int nt  = l & 7;                      // 0..7
    const int m0  = mt * 128;
    const int n0  = nt * 128;

    const int r = lane & 15;
    const int q = lane >> 4;

    const short* ap = A + (size_t)(m0 + wrow * 64 + r) * KP + q * 8;
    const short* bp = B + (size_t)(n0 + wcol * 64 + r) * KP + q * 8;

    f32x4 acc[4][4] = {};
    bf16x8 a0[4], b0[4], a1[4], b1[4];

#pragma unroll
    for (int i = 0; i < 4; ++i) {
        a0[i] = *(const bf16x8*)(ap + (size_t)i * 16 * KP);
        b0[i] = *(const bf16x8*)(bp + (size_t)i * 16 * KP);
    }

    for (int k0 = 0; k0 < KP - 64; k0 += 64) {
#pragma unroll
        for (int i = 0; i < 4; ++i) {           // prefetch half 2 (k0+32)
            a1[i] = *(const bf16x8*)(ap + (size_t)i * 16 * KP + k0 + 32);
            b1[i] = *(const bf16x8*)(bp + (size_t)i * 16 * KP + k0 + 32);
        }
#pragma unroll
        for (int i = 0; i < 4; ++i)
#pragma unroll
            for (int j = 0; j < 4; ++j)
                acc[i][j] = __builtin_amdgcn_mfma_f32_16x16x32_bf16(a0[i], b0[j], acc[i][j], 0, 0, 0);
#pragma unroll
        for (int i = 0; i < 4; ++i) {           // prefetch half 1 of next iter (k0+64)
            a0[i] = *(const bf16x8*)(ap + (size_t)i * 16 * KP + k0 + 64);
            b0[i] = *(const bf16x8*)(bp + (size_t)i * 16 * KP + k0 + 64);
        }
#pragma unroll
        for (int i = 0; i < 4; ++i)
#pragma unroll
            for (int j = 0; j < 4; ++j)
                acc[i][j] = __builtin_amdgcn_mfma_f32_16x16x32_bf16(a1[i], b1[j], acc[i][j], 0, 0, 0);
    }
    // tail: k0 = KP-64 (halves at KP-64, KP-32)
#pragma unroll
    for (int i = 0; i < 4; ++i) {
        a1[i] = *(const bf16x8*)(ap + (size_t)i * 16 * KP + (KP - 32));
        b1[i] = *(const bf16x8*)(bp + (size_t)i * 16 * KP + (KP - 32));
    }
#pragma unroll
    for (int i = 0; i < 4; ++i)
#pragma unroll
        for (int j = 0; j < 4; ++j)
            acc[i][j] = __builtin_amdgcn_mfma_f32_16x16x32_bf16(a0[i], b0[j], acc[i][j], 0, 0, 0);
#pragma unroll
    for (int i = 0; i < 4; ++i)
#pragma unroll
        for (int j = 0; j < 4; ++j)
            acc[i][j] = __builtin_amdgcn_mfma_f32_16x16x32_bf16(a1[i], b1[j], acc[i][j], 0, 0, 0);

    // epilogue: C/D layout col = lane&15, row = (lane>>4)*4 + reg  [m89/m91]
    const int rr0 = m0 + wrow * 64 + (q << 2);
    const int c0  = n0 + wcol * 64 + r;
    float bv[4];
#pragma unroll
    for (int j = 0; j < 4; ++j) bv[j] = bias[c0 + j * 16];
#pragma unroll
    for (int i = 0; i < 4; ++i)
#pragma unroll
        for (int rg = 0; rg < 4; ++rg) {
            float* cp = C + (size_t)(rr0 + i * 16 + rg) * NOUT;
#pragma unroll
            for (int j = 0; j < 4; ++j)
                cp[c0 + j * 16] = acc[i][j][rg] + bv[j];
        }
}

extern "C" void kernel_launch(void* const* d_in, const int* in_sizes, int n_in,
                              void* d_out, int out_size, void* d_ws, size_t ws_size,
                              hipStream_t stream) {
    const float* x    = (const float*)d_in[0];   // [8, 8192, 1024]
    const float* W    = (const float*)d_in[1];   // [1024, 1056]
    const float* bias = (const float*)d_in[2];   // [1024]
    float* out = (float*)d_out;                  // [8, 2048, 1024]

    // workspace: Wb bf16 [1024*KP] then h bf16 [16384*KP]
    short* Wb = (short*)d_ws;
    short* h  = (short*)((char*)d_ws + (size_t)NOUT * KP * sizeof(short));

    prep    <<<dim3(MROWS + NOUT), dim3(256), 0, stream>>>(x, W, h, Wb);
    gemm_reg<<<dim3((MROWS / 128) * (NOUT / 128)), dim3(256), 0, stream>>>(h, Wb, bias, out);
}